// Round 1
// 950.338 us; speedup vs baseline: 1.1777x; 1.1777x over previous
//
#include <hip/hip_runtime.h>
#include <hip/hip_bf16.h>
#include <math.h>

typedef unsigned short U16;
typedef __bf16 bf16x8 __attribute__((ext_vector_type(8)));
typedef float floatx4 __attribute__((ext_vector_type(4)));
typedef unsigned short ushort8 __attribute__((ext_vector_type(8)));

#define C_CH 512
#define HF 50
#define WF 75
#define NROIS 512
#define FC_IN 25088     // 512*49
#define FC_DIM 4096
#define NHEAD 105       // 84 + 21
#define NHEAD_PAD 128
#define OUT_LOCS (NROIS * 84)   // 43008

__device__ __forceinline__ float b2f(U16 u) {
    union { unsigned int i; float f; } x; x.i = ((unsigned int)u) << 16; return x.f;
}
__device__ __forceinline__ U16 f2b(float f) {
    union { float f; unsigned int i; } x; x.f = f;
    unsigned int r = x.i + 0x7fffu + ((x.i >> 16) & 1u);
    return (U16)(r >> 16);
}

// async global->LDS 16B: lds dest = wave-uniform base + lane*16
__device__ __forceinline__ void gld_lds16(const U16* g, U16* lds_base, int lane) {
#if __has_builtin(__builtin_amdgcn_global_load_lds)
    typedef const __attribute__((address_space(1))) unsigned int* gas1;
    typedef __attribute__((address_space(3))) unsigned int* las3;
    __builtin_amdgcn_global_load_lds((gas1)(unsigned long long)g,
                                     (las3)(unsigned int)(unsigned long long)lds_base,
                                     16, 0, 0);
#else
    *(floatx4*)(lds_base + lane * 8) = *(const floatx4*)g;
#endif
}

// ---------------------------------------------------------------------------
// Dtype detector: flags[0]=1 iff weights/x/out are f32; flags[1]=1 iff rois f32.
// ---------------------------------------------------------------------------
__global__ void detect_kernel(const unsigned int* __restrict__ w1,
                              const unsigned int* __restrict__ rois,
                              int* __restrict__ flags) {
    __shared__ int cnt_w, cnt_r;
    if (threadIdx.x == 0) { cnt_w = 0; cnt_r = 0; }
    __syncthreads();
    int lw = 0;
    for (int i = threadIdx.x; i < 2048; i += 256) {
        const unsigned int w = w1[i];
        const unsigned int e = (w >> 7) & 0xFFu;
        if ((e >= 90u && e <= 130u) || (w & 0x7FFFu) == 0u) lw++;
    }
    int lr = 0;
    for (int i = threadIdx.x; i < 512; i += 256) {
        union { unsigned int u; float f; } v; v.u = rois[i];
        const float f = v.f;
        if (f >= 0.0f && f <= 1300.0f && f == floorf(f)) lr++;
    }
    atomicAdd(&cnt_w, lw);
    atomicAdd(&cnt_r, lr);
    __syncthreads();
    if (threadIdx.x == 0) {
        flags[0] = (cnt_w < 1024) ? 1 : 0;
        flags[1] = (cnt_r >= 256) ? 1 : 0;
    }
}

// ---------------------------------------------------------------------------
// ROI adaptive max pool. grid (512 rois, 16 channel-groups of 32), 256 thr.
// ---------------------------------------------------------------------------
__global__ void roi_pool_kernel(const void* __restrict__ feat_,
                                const void* __restrict__ rois_,
                                const int* __restrict__ flags,
                                U16* __restrict__ pool) {
    const int n = blockIdx.x;
    const int ch0 = blockIdx.y * 32;
    const int t = threadIdx.x;
    const int f32w = flags[0];
    const int f32r = flags[1];
    __shared__ int rs[7], re_[7], cs[7], ce_[7];

    float c4[4];
    if (f32r) {
        const float* r = (const float*)rois_ + n * 4;
        c4[0] = r[0]; c4[1] = r[1]; c4[2] = r[2]; c4[3] = r[3];
    } else {
        const U16* r = (const U16*)rois_ + n * 4;
        c4[0] = b2f(r[0]); c4[1] = b2f(r[1]); c4[2] = b2f(r[2]); c4[3] = b2f(r[3]);
    }
    const int x1 = (int)(c4[0] * 0.0625f);
    const int y1 = (int)(c4[1] * 0.0625f);
    const int x2 = (int)(c4[2] * 0.0625f);
    const int y2 = (int)(c4[3] * 0.0625f);
    const int h = y2 - y1 + 1;
    const int w = x2 - x1 + 1;
    if (t < 7) {
        rs[t] = y1 + (t * h) / 7;
        re_[t] = y1 + ((t + 1) * h + 6) / 7;
        cs[t] = x1 + (t * w) / 7;
        ce_[t] = x1 + ((t + 1) * w + 6) / 7;
    }
    __syncthreads();

    const float* featf = (const float*)feat_;
    const U16* featu = (const U16*)feat_;

    for (int o = t; o < 32 * 49; o += 256) {
        const int ch = ch0 + o / 49;
        const int b = o % 49;
        const int ph = b / 7;
        const int pw = b - ph * 7;
        const int r0 = rs[ph], r1 = re_[ph];
        const int c0 = cs[pw], c1 = ce_[pw];
        const int base = ch * (HF * WF);
        float m = -1.0e4f;
        if (f32w) {
            for (int r = r0; r < r1; ++r) {
                const int rr = r < (HF - 1) ? r : (HF - 1);
                const float* fr = featf + base + rr * WF;
                for (int c = c0; c < c1; ++c) {
                    const int cc = c < (WF - 1) ? c : (WF - 1);
                    const float v = fr[cc];
                    m = (m > v) ? m : v;
                }
            }
        } else {
            for (int r = r0; r < r1; ++r) {
                const int rr = r < (HF - 1) ? r : (HF - 1);
                const U16* fr = featu + base + rr * WF;
                for (int c = c0; c < c1; ++c) {
                    const int cc = c < (WF - 1) ? c : (WF - 1);
                    const float v = b2f(fr[cc]);
                    m = (m > v) ? m : v;
                }
            }
        }
        m = fminf(fmaxf(m, -1.0e4f), 1.0e4f);
        pool[(size_t)n * FC_IN + ch * 49 + b] = f2b(m);
    }
}

// ---------------------------------------------------------------------------
// m97-style GEMM with FUSED B transpose+cast:
//   Cpart[s] = A[M,K](bf16) @ B[K,N](f32 or bf16) over k in [s*Ks,(s+1)*Ks).
// 128x128 tile, BK=32, 256 thr = 2x2 waves each 64x64 (16 mfma 16x16x32).
// A: global_load_lds width-16 into a_lds[row][32] (verified m97 layout).
// B: reg-staged — thread loads 8 float2 (2 cols x 8 k, coalesced 256B/row),
//    cvt f32->bf16 in-reg, ds_write_b128 transposed into b_lds with 80B
//    padded rows (write: 2-way bank alias = free; read: ~b128 baseline).
// Next B tile prefetched into regs during MFMA (drained by trailing barrier).
// ---------------------------------------------------------------------------
#define GBM 128
#define GBN 128
#define GBK 32
#define BROW 40   // U16 per b_lds row = 80 bytes (64B data + 16B pad)

__launch_bounds__(256, 2)
__global__ void gemm_fused_kernel(const U16* __restrict__ A, int lda,
                                  const void* __restrict__ B, int ldb,
                                  float* __restrict__ Cpart,
                                  int M, int N, int Ks,
                                  const int* __restrict__ flags) {
    __shared__ __align__(16) U16 a_lds[GBM * GBK];   // 8 KB
    __shared__ __align__(16) U16 b_lds[GBN * BROW];  // 10 KB

    const int t = threadIdx.x;
    const int wave = t >> 6, lane = t & 63;
    const int ln = lane & 15, q = lane >> 4;
    const int wm = wave >> 1, wn = wave & 1;
    const int bm = blockIdx.y * GBM, bn = blockIdx.x * GBN;
    const int s = blockIdx.z;
    const int kb = s * Ks, ke = kb + Ks;
    float* Cp = Cpart + (size_t)s * M * N;
    const int f32b = flags[0];

    floatx4 acc[4][4];
#pragma unroll
    for (int i = 0; i < 4; ++i)
#pragma unroll
        for (int j = 0; j < 4; ++j) acc[i][j] = (floatx4)0.0f;

    // A staging: 8 slots of 16 rows; wave handles slots wave*2, wave*2+1
    const int slot0 = wave * 2;
    const int rsl = lane >> 2;          // row within slot
    const int c8 = (lane & 3) * 8;      // k-elem offset
    const U16* Ag0 = A + (size_t)(bm + slot0 * 16 + rsl) * lda + c8;
    const U16* Ag1 = A + (size_t)(bm + slot0 * 16 + 16 + rsl) * lda + c8;
    U16* al0 = &a_lds[slot0 * 512];
    U16* al1 = &a_lds[(slot0 + 1) * 512];

    // B staging thread map: 2 consecutive cols x 8 k-rows per thread
    const int np = (t & 63) * 2;        // col pair base 0..126
    const int kg = (t >> 6) * 8;        // k offset within tile {0,8,16,24}
    U16* bw0 = &b_lds[(size_t)np * BROW + kg];
    U16* bw1 = &b_lds[(size_t)(np + 1) * BROW + kg];

    if (f32b) {
        const float* bp = (const float*)B + (size_t)(kb + kg) * ldb + bn + np;
        typedef float float2v __attribute__((ext_vector_type(2)));
        float2v v[8];
#pragma unroll
        for (int j = 0; j < 8; ++j) v[j] = *(const float2v*)(bp + (size_t)j * ldb);
        bp += (size_t)GBK * ldb;

        for (int k0 = kb; k0 < ke; k0 += GBK) {
            gld_lds16(Ag0 + k0, al0, lane);
            gld_lds16(Ag1 + k0, al1, lane);
            union { __bf16 b[8]; ushort8 s8; } h0, h1;
#pragma unroll
            for (int j = 0; j < 8; ++j) {
                h0.b[j] = (__bf16)v[j].x;
                h1.b[j] = (__bf16)v[j].y;
            }
            *(ushort8*)bw0 = h0.s8;
            *(ushort8*)bw1 = h1.s8;
            __syncthreads();   // drains A vmcnt + B lgkm

            bf16x8 av[4], bv[4];
#pragma unroll
            for (int mt = 0; mt < 4; ++mt)
                av[mt] = *(const bf16x8*)&a_lds[(wm * 64 + mt * 16 + ln) * GBK + q * 8];
#pragma unroll
            for (int nt = 0; nt < 4; ++nt)
                bv[nt] = *(const bf16x8*)&b_lds[(size_t)(wn * 64 + nt * 16 + ln) * BROW + q * 8];

            if (k0 + GBK < ke) {   // prefetch next B tile under MFMA
#pragma unroll
                for (int j = 0; j < 8; ++j) v[j] = *(const float2v*)(bp + (size_t)j * ldb);
                bp += (size_t)GBK * ldb;
            }

#pragma unroll
            for (int mt = 0; mt < 4; ++mt)
#pragma unroll
                for (int nt = 0; nt < 4; ++nt)
                    acc[mt][nt] = __builtin_amdgcn_mfma_f32_16x16x32_bf16(
                        av[mt], bv[nt], acc[mt][nt], 0, 0, 0);
            __syncthreads();
        }
    } else {
        const int ldw = ldb >> 1;   // dwords per B row
        const unsigned int* bp = (const unsigned int*)B +
                                 (((size_t)(kb + kg) * ldb + bn + np) >> 1);
        unsigned int v[8];
#pragma unroll
        for (int j = 0; j < 8; ++j) v[j] = bp[(size_t)j * ldw];
        bp += (size_t)GBK * ldw;

        for (int k0 = kb; k0 < ke; k0 += GBK) {
            gld_lds16(Ag0 + k0, al0, lane);
            gld_lds16(Ag1 + k0, al1, lane);
            union { U16 u[8]; ushort8 s8; } h0, h1;
#pragma unroll
            for (int j = 0; j < 8; ++j) {
                h0.u[j] = (U16)(v[j] & 0xffffu);
                h1.u[j] = (U16)(v[j] >> 16);
            }
            *(ushort8*)bw0 = h0.s8;
            *(ushort8*)bw1 = h1.s8;
            __syncthreads();

            bf16x8 av[4], bv[4];
#pragma unroll
            for (int mt = 0; mt < 4; ++mt)
                av[mt] = *(const bf16x8*)&a_lds[(wm * 64 + mt * 16 + ln) * GBK + q * 8];
#pragma unroll
            for (int nt = 0; nt < 4; ++nt)
                bv[nt] = *(const bf16x8*)&b_lds[(size_t)(wn * 64 + nt * 16 + ln) * BROW + q * 8];

            if (k0 + GBK < ke) {
#pragma unroll
                for (int j = 0; j < 8; ++j) v[j] = bp[(size_t)j * ldw];
                bp += (size_t)GBK * ldw;
            }

#pragma unroll
            for (int mt = 0; mt < 4; ++mt)
#pragma unroll
                for (int nt = 0; nt < 4; ++nt)
                    acc[mt][nt] = __builtin_amdgcn_mfma_f32_16x16x32_bf16(
                        av[mt], bv[nt], acc[mt][nt], 0, 0, 0);
            __syncthreads();
        }
    }

#pragma unroll
    for (int nt = 0; nt < 4; ++nt) {
        const int col = bn + wn * 64 + nt * 16 + ln;
#pragma unroll
        for (int mt = 0; mt < 4; ++mt) {
            const int row = bm + wm * 64 + mt * 16 + q * 4;
#pragma unroll
            for (int r = 0; r < 4; ++r)
                Cp[(size_t)(row + r) * N + col] = acc[mt][nt][r];
        }
    }
}

// ---------------------------------------------------------------------------
// m97-style GEMM, B pre-transposed bf16 (kept for the small heads matmul).
// ---------------------------------------------------------------------------
__launch_bounds__(256, 2)
__global__ void gemm_tn_kernel(const U16* __restrict__ A, int lda,
                               const U16* __restrict__ BT, int ldb,
                               float* __restrict__ Cpart,
                               int M, int N, int Ks) {
    __shared__ __align__(16) U16 a_lds[GBM * GBK];  // 8 KB
    __shared__ __align__(16) U16 b_lds[GBN * GBK];  // 8 KB

    const int t = threadIdx.x;
    const int wave = t >> 6, lane = t & 63;
    const int ln = lane & 15, q = lane >> 4;
    const int wm = wave >> 1, wn = wave & 1;
    const int bm = blockIdx.y * GBM, bn = blockIdx.x * GBN;
    const int s = blockIdx.z;
    const int kb = s * Ks, ke = kb + Ks;
    float* Cp = Cpart + (size_t)s * M * N;

    floatx4 acc[4][4];
#pragma unroll
    for (int i = 0; i < 4; ++i)
#pragma unroll
        for (int j = 0; j < 4; ++j) acc[i][j] = (floatx4)0.0f;

    const int slot0 = wave * 2;
    const int rsl = lane >> 2;
    const int c8 = (lane & 3) * 8;
    const U16* Ag0 = A + (size_t)(bm + slot0 * 16 + rsl) * lda + c8;
    const U16* Ag1 = A + (size_t)(bm + slot0 * 16 + 16 + rsl) * lda + c8;
    const U16* Bg0 = BT + (size_t)(bn + slot0 * 16 + rsl) * ldb + c8;
    const U16* Bg1 = BT + (size_t)(bn + slot0 * 16 + 16 + rsl) * ldb + c8;
    U16* al0 = &a_lds[slot0 * 512];
    U16* al1 = &a_lds[(slot0 + 1) * 512];
    U16* bl0 = &b_lds[slot0 * 512];
    U16* bl1 = &b_lds[(slot0 + 1) * 512];

    for (int k0 = kb; k0 < ke; k0 += GBK) {
        gld_lds16(Ag0 + k0, al0, lane);
        gld_lds16(Ag1 + k0, al1, lane);
        gld_lds16(Bg0 + k0, bl0, lane);
        gld_lds16(Bg1 + k0, bl1, lane);
        __syncthreads();

        bf16x8 av[4], bv[4];
#pragma unroll
        for (int mt = 0; mt < 4; ++mt)
            av[mt] = *(const bf16x8*)&a_lds[(wm * 64 + mt * 16 + ln) * GBK + q * 8];
#pragma unroll
        for (int nt = 0; nt < 4; ++nt)
            bv[nt] = *(const bf16x8*)&b_lds[(wn * 64 + nt * 16 + ln) * GBK + q * 8];

#pragma unroll
        for (int mt = 0; mt < 4; ++mt)
#pragma unroll
            for (int nt = 0; nt < 4; ++nt)
                acc[mt][nt] = __builtin_amdgcn_mfma_f32_16x16x32_bf16(
                    av[mt], bv[nt], acc[mt][nt], 0, 0, 0);
        __syncthreads();
    }

#pragma unroll
    for (int nt = 0; nt < 4; ++nt) {
        const int col = bn + wn * 64 + nt * 16 + ln;
#pragma unroll
        for (int mt = 0; mt < 4; ++mt) {
            const int row = bm + wm * 64 + mt * 16 + q * 4;
#pragma unroll
            for (int r = 0; r < 4; ++r)
                Cp[(size_t)(row + r) * N + col] = acc[mt][nt][r];
        }
    }
}

// sum partials + bias, optional relu, -> bf16
__global__ void reduce_act_kernel(const float* __restrict__ Cpart,
                                  const U16* __restrict__ bias,
                                  U16* __restrict__ Cout,
                                  int MN, int N, int S, int do_relu) {
    const int i4 = (blockIdx.x * 256 + threadIdx.x) * 4;
    if (i4 >= MN) return;
    floatx4 sum = *(const floatx4*)&Cpart[i4];
    for (int s = 1; s < S; ++s)
        sum += *(const floatx4*)&Cpart[(size_t)s * MN + i4];
    const int nb = i4 & (N - 1);
    U16 o[4];
#pragma unroll
    for (int j = 0; j < 4; ++j) {
        float v = sum[j] + b2f(bias[nb + j]);
        if (do_relu) { v = v > 0.0f ? v : 0.0f; v = fminf(v, 1.0e4f); }
        o[j] = f2b(v);
    }
    *(unsigned long long*)&Cout[i4] = *(unsigned long long*)o;
}

// pack heads transposed: WhT [128][4096] bf16 (rows>=105 zero), bh[128]
__global__ void pack_headsT_kernel(const void* __restrict__ W_loc,
                                   const void* __restrict__ W_score,
                                   const U16* __restrict__ b_loc,
                                   const U16* __restrict__ b_score,
                                   const int* __restrict__ flags,
                                   U16* __restrict__ WhT, U16* __restrict__ bh) {
    const int idx = blockIdx.x * 256 + threadIdx.x;   // 128*4096
    const int c = idx >> 12;
    const int k = idx & 4095;
    const int f32w = flags[0];
    U16 v = 0;
    if (f32w) {
        if (c < 84) v = f2b(((const float*)W_loc)[(size_t)k * 84 + c]);
        else if (c < NHEAD) v = f2b(((const float*)W_score)[(size_t)k * 21 + (c - 84)]);
    } else {
        if (c < 84) v = ((const U16*)W_loc)[(size_t)k * 84 + c];
        else if (c < NHEAD) v = ((const U16*)W_score)[(size_t)k * 21 + (c - 84)];
    }
    WhT[idx] = v;
    if (idx < NHEAD_PAD) {
        U16 bb = 0;
        if (idx < 84) bb = b_loc[idx];
        else if (idx < NHEAD) bb = b_score[idx - 84];
        bh[idx] = bb;
    }
}

// reduce head partials [S][512][128] + bias -> scattered output
__global__ void head_reduce_kernel(const float* __restrict__ Cpart,
                                   const U16* __restrict__ bh,
                                   const int* __restrict__ flags,
                                   void* __restrict__ out, int S) {
    const int idx = blockIdx.x * 256 + threadIdx.x;
    if (idx >= NROIS * NHEAD_PAD) return;
    const int m = idx >> 7;
    const int c = idx & 127;
    float s = 0.0f;
    for (int ss = 0; ss < S; ++ss)
        s += Cpart[(size_t)ss * (NROIS * NHEAD_PAD) + idx];
    s += b2f(bh[c]);
    if (c >= NHEAD) return;
    const int dst = (c < 84) ? (m * 84 + c) : (OUT_LOCS + m * 21 + (c - 84));
    if (flags[0]) ((float*)out)[dst] = s;
    else ((U16*)out)[dst] = f2b(s);
}

// ======================= fallback path (round-2, verified) =================
#define BM 128
#define BN 64
#define BK 32

__launch_bounds__(256, 2)
__global__ void gemm_bias_kernel(const U16* __restrict__ A,
                                 const void* __restrict__ B,
                                 const U16* __restrict__ bias,
                                 U16* __restrict__ Cout,
                                 int M, int N, int K, int do_relu,
                                 const int* __restrict__ flags, int use_flag) {
    __shared__ U16 a_lds[BM][BK];
    __shared__ U16 b_lds[BK][80];
    const int b_f32 = use_flag ? flags[0] : 0;
    const int t = threadIdx.x;
    const int wave = t >> 6, lane = t & 63;
    const int ln = lane & 15, q = lane >> 4;
    const int wm = wave >> 1, wn = wave & 1;
    const int bm = blockIdx.y * BM, bn = blockIdx.x * BN;
    floatx4 acc[4][2];
#pragma unroll
    for (int i = 0; i < 4; ++i)
#pragma unroll
        for (int j = 0; j < 2; ++j) acc[i][j] = (floatx4)0.0f;
    const int arow = t >> 2, acol = (t & 3) * 8;
    const int bk = t >> 3, bn8 = (t & 7) * 8;
    const int browp = ((bk & 7) << 2) | (bk >> 3);
    const U16* Ap0 = A + (size_t)(bm + arow) * K + acol;
    const U16* Ap1 = A + (size_t)(bm + 64 + arow) * K + acol;
    const U16* Bp16 = (const U16*)B + (size_t)bk * N + bn + bn8;
    const float* Bp32 = (const float*)B + (size_t)bk * N + bn + bn8;
    for (int k0 = 0; k0 < K; k0 += BK) {
        *(floatx4*)&a_lds[arow][acol] = *(const floatx4*)(Ap0 + k0);
        *(floatx4*)&a_lds[64 + arow][acol] = *(const floatx4*)(Ap1 + k0);
        if (b_f32) {
            const float* src = Bp32 + (size_t)k0 * N;
            union { U16 u[8]; floatx4 v; } tmp;
#pragma unroll
            for (int j = 0; j < 8; ++j) tmp.u[j] = f2b(src[j]);
            *(floatx4*)&b_lds[browp][bn8] = tmp.v;
        } else {
            *(floatx4*)&b_lds[browp][bn8] = *(const floatx4*)(Bp16 + (size_t)k0 * N);
        }
        __syncthreads();
        bf16x8 av[4];
#pragma unroll
        for (int mt = 0; mt < 4; ++mt)
            av[mt] = *(const bf16x8*)&a_lds[wm * 64 + mt * 16 + ln][q * 8];
        union { U16 u[8]; bf16x8 v; } bu[2];
#pragma unroll
        for (int nt = 0; nt < 2; ++nt) {
            const int n = wn * 32 + nt * 16 + ln;
#pragma unroll
            for (int j = 0; j < 8; ++j) bu[nt].u[j] = b_lds[(j << 2) | q][n];
        }
#pragma unroll
        for (int mt = 0; mt < 4; ++mt)
#pragma unroll
            for (int nt = 0; nt < 2; ++nt)
                acc[mt][nt] = __builtin_amdgcn_mfma_f32_16x16x32_bf16(
                    av[mt], bu[nt].v, acc[mt][nt], 0, 0, 0);
        __syncthreads();
    }
#pragma unroll
    for (int nt = 0; nt < 2; ++nt) {
        const int col = bn + wn * 32 + nt * 16 + ln;
        const float bv = b2f(bias[col]);
#pragma unroll
        for (int mt = 0; mt < 4; ++mt) {
            const int row = bm + wm * 64 + mt * 16 + q * 4;
#pragma unroll
            for (int r = 0; r < 4; ++r) {
                float v = acc[mt][nt][r] + bv;
                if (do_relu) { v = v > 0.0f ? v : 0.0f; v = fminf(v, 1.0e4f); }
                Cout[(size_t)(row + r) * N + col] = f2b(v);
            }
        }
    }
}

__global__ void pack_heads_kernel(const void* __restrict__ W_loc,
                                  const void* __restrict__ W_score,
                                  const U16* __restrict__ b_loc,
                                  const U16* __restrict__ b_score,
                                  const int* __restrict__ flags,
                                  U16* __restrict__ Wh, U16* __restrict__ bh) {
    const int k = blockIdx.x;
    const int c = threadIdx.x;
    const int f32w = flags[0];
    U16 v = 0;
    if (f32w) {
        if (c < 84) v = f2b(((const float*)W_loc)[k * 84 + c]);
        else if (c < NHEAD) v = f2b(((const float*)W_score)[k * 21 + (c - 84)]);
    } else {
        if (c < 84) v = ((const U16*)W_loc)[k * 84 + c];
        else if (c < NHEAD) v = ((const U16*)W_score)[k * 21 + (c - 84)];
    }
    Wh[k * NHEAD_PAD + c] = v;
    if (k == 0) {
        U16 bb = 0;
        if (c < 84) bb = b_loc[c];
        else if (c < NHEAD) bb = b_score[c - 84];
        bh[c] = bb;
    }
}

__global__ void scatter_out_kernel(const U16* __restrict__ Chead,
                                   const int* __restrict__ flags,
                                   void* __restrict__ out) {
    const int idx = blockIdx.x * 256 + threadIdx.x;
    if (idx >= NROIS * NHEAD) return;
    const int f32o = flags[0];
    const int m = idx / NHEAD;
    const int c = idx - m * NHEAD;
    const U16 v = Chead[m * NHEAD_PAD + c];
    const int dst = (c < 84) ? (m * 84 + c) : (OUT_LOCS + m * 21 + (c - 84));
    if (f32o) ((float*)out)[dst] = b2f(v);
    else ((U16*)out)[dst] = v;
}

// ===========================================================================
extern "C" void kernel_launch(void* const* d_in, const int* in_sizes, int n_in,
                              void* d_out, int out_size, void* d_ws, size_t ws_size,
                              hipStream_t stream) {
    const void* x       = d_in[0];
    const void* rois    = d_in[1];
    const void* W1      = d_in[2];
    const U16* b1       = (const U16*)d_in[3];
    const void* W2      = d_in[4];
    const U16* b2       = (const U16*)d_in[5];
    const void* W_loc   = d_in[6];
    const U16* b_loc    = (const U16*)d_in[7];
    const void* W_score = d_in[8];
    const U16* b_score  = (const U16*)d_in[9];

    int* flags = (int*)d_ws;
    char* p = (char*)d_ws + 256;
    U16* pool = (U16*)p;                       p += (size_t)NROIS * FC_IN * 2;
    U16* fc1  = (U16*)p;                       p += (size_t)NROIS * FC_DIM * 2;
    U16* fc2  = (U16*)p;                       p += (size_t)NROIS * FC_DIM * 2;

    detect_kernel<<<1, 256, 0, stream>>>((const unsigned int*)W1,
                                         (const unsigned int*)rois, flags);
    roi_pool_kernel<<<dim3(NROIS, 16), 256, 0, stream>>>(x, rois, flags, pool);

    // fast path: fused-transpose GEMMs, needs ~69 MB of ws
    char* pf = p;
    U16* WhT = (U16*)pf;  pf += (size_t)NHEAD_PAD * FC_DIM * 2;
    U16* bh  = (U16*)pf;  pf += 256;
    float* Cpart = (float*)pf; pf += (size_t)4 * NROIS * FC_DIM * 4;
    const size_t need_fast = (size_t)(pf - (char*)d_ws);

    if (ws_size >= need_fast) {
        pack_headsT_kernel<<<(NHEAD_PAD * FC_DIM) / 256, 256, 0, stream>>>(
            W_loc, W_score, b_loc, b_score, flags, WhT, bh);

        // FC1: M=512 N=4096 K=25088, splitK=4 (Ks=6272), grid 512 blocks.
        // B = raw W1 [K][N] (f32 or bf16) — transpose+cast fused into staging.
        gemm_fused_kernel<<<dim3(FC_DIM / GBN, NROIS / GBM, 4), 256, 0, stream>>>(
            pool, FC_IN, W1, FC_DIM, Cpart, NROIS, FC_DIM, FC_IN / 4, flags);
        reduce_act_kernel<<<(NROIS * FC_DIM / 4) / 256, 256, 0, stream>>>(
            Cpart, b1, fc1, NROIS * FC_DIM, FC_DIM, 4, 1);

        // FC2: K=4096, splitK=4 (Ks=1024)
        gemm_fused_kernel<<<dim3(FC_DIM / GBN, NROIS / GBM, 4), 256, 0, stream>>>(
            fc1, FC_DIM, W2, FC_DIM, Cpart, NROIS, FC_DIM, FC_DIM / 4, flags);
        reduce_act_kernel<<<(NROIS * FC_DIM / 4) / 256, 256, 0, stream>>>(
            Cpart, b2, fc2, NROIS * FC_DIM, FC_DIM, 4, 1);

        // heads: N=128, K=4096, splitK=32 (Ks=128) — small, keep bf16-BT path
        gemm_tn_kernel<<<dim3(1, NROIS / GBM, 32), 256, 0, stream>>>(
            fc2, FC_DIM, WhT, FC_DIM, Cpart, NROIS, NHEAD_PAD, FC_DIM / 32);
        head_reduce_kernel<<<(NROIS * NHEAD_PAD) / 256, 256, 0, stream>>>(
            Cpart, bh, flags, d_out, 32);
    } else {
        // fallback (round-2 verified path, ~36 MB ws)
        U16* Wh    = (U16*)p;
        U16* bhf   = Wh + (size_t)FC_DIM * NHEAD_PAD;
        U16* Chead = bhf + NHEAD_PAD;
        pack_heads_kernel<<<FC_DIM, NHEAD_PAD, 0, stream>>>(W_loc, W_score, b_loc,
                                                            b_score, flags, Wh, bhf);
        gemm_bias_kernel<<<dim3(FC_DIM / BN, NROIS / BM), 256, 0, stream>>>(
            pool, W1, b1, fc1, NROIS, FC_DIM, FC_IN, 1, flags, 1);
        gemm_bias_kernel<<<dim3(FC_DIM / BN, NROIS / BM), 256, 0, stream>>>(
            fc1, W2, b2, fc2, NROIS, FC_DIM, FC_DIM, 1, flags, 1);
        gemm_bias_kernel<<<dim3(NHEAD_PAD / BN, NROIS / BM), 256, 0, stream>>>(
            fc2, Wh, bhf, Chead, NROIS, NHEAD_PAD, FC_DIM, 0, flags, 0);
        scatter_out_kernel<<<(NROIS * NHEAD + 255) / 256, 256, 0, stream>>>(
            Chead, flags, d_out);
    }
}

// Round 2
// 902.125 us; speedup vs baseline: 1.2407x; 1.0534x over previous
//
#include <hip/hip_runtime.h>
#include <hip/hip_bf16.h>
#include <math.h>

typedef unsigned short U16;
typedef __bf16 bf16x8 __attribute__((ext_vector_type(8)));
typedef float floatx4 __attribute__((ext_vector_type(4)));
typedef unsigned short ushort8 __attribute__((ext_vector_type(8)));

#define C_CH 512
#define HF 50
#define WF 75
#define NROIS 512
#define FC_IN 25088     // 512*49
#define FC_DIM 4096
#define NHEAD 105       // 84 + 21
#define NHEAD_PAD 128
#define OUT_LOCS (NROIS * 84)   // 43008

__device__ __forceinline__ float b2f(U16 u) {
    union { unsigned int i; float f; } x; x.i = ((unsigned int)u) << 16; return x.f;
}
__device__ __forceinline__ U16 f2b(float f) {
    union { float f; unsigned int i; } x; x.f = f;
    unsigned int r = x.i + 0x7fffu + ((x.i >> 16) & 1u);
    return (U16)(r >> 16);
}

// async global->LDS 16B: lds dest = wave-uniform base + lane*16
__device__ __forceinline__ void gld_lds16(const U16* g, U16* lds_base, int lane) {
#if __has_builtin(__builtin_amdgcn_global_load_lds)
    typedef const __attribute__((address_space(1))) unsigned int* gas1;
    typedef __attribute__((address_space(3))) unsigned int* las3;
    __builtin_amdgcn_global_load_lds((gas1)(unsigned long long)g,
                                     (las3)(unsigned int)(unsigned long long)lds_base,
                                     16, 0, 0);
#else
    *(floatx4*)(lds_base + lane * 8) = *(const floatx4*)g;
#endif
}

// ---------------------------------------------------------------------------
// Dtype detector: flags[0]=1 iff weights/x/out are f32; flags[1]=1 iff rois f32.
// ---------------------------------------------------------------------------
__global__ void detect_kernel(const unsigned int* __restrict__ w1,
                              const unsigned int* __restrict__ rois,
                              int* __restrict__ flags) {
    __shared__ int cnt_w, cnt_r;
    if (threadIdx.x == 0) { cnt_w = 0; cnt_r = 0; }
    __syncthreads();
    int lw = 0;
    for (int i = threadIdx.x; i < 2048; i += 256) {
        const unsigned int w = w1[i];
        const unsigned int e = (w >> 7) & 0xFFu;
        if ((e >= 90u && e <= 130u) || (w & 0x7FFFu) == 0u) lw++;
    }
    int lr = 0;
    for (int i = threadIdx.x; i < 512; i += 256) {
        union { unsigned int u; float f; } v; v.u = rois[i];
        const float f = v.f;
        if (f >= 0.0f && f <= 1300.0f && f == floorf(f)) lr++;
    }
    atomicAdd(&cnt_w, lw);
    atomicAdd(&cnt_r, lr);
    __syncthreads();
    if (threadIdx.x == 0) {
        flags[0] = (cnt_w < 1024) ? 1 : 0;
        flags[1] = (cnt_r >= 256) ? 1 : 0;
    }
}

// ---------------------------------------------------------------------------
// ROI adaptive max pool. grid (512 rois, 16 channel-groups of 32), 256 thr.
// ---------------------------------------------------------------------------
__global__ void roi_pool_kernel(const void* __restrict__ feat_,
                                const void* __restrict__ rois_,
                                const int* __restrict__ flags,
                                U16* __restrict__ pool) {
    const int n = blockIdx.x;
    const int ch0 = blockIdx.y * 32;
    const int t = threadIdx.x;
    const int f32w = flags[0];
    const int f32r = flags[1];
    __shared__ int rs[7], re_[7], cs[7], ce_[7];

    float c4[4];
    if (f32r) {
        const float* r = (const float*)rois_ + n * 4;
        c4[0] = r[0]; c4[1] = r[1]; c4[2] = r[2]; c4[3] = r[3];
    } else {
        const U16* r = (const U16*)rois_ + n * 4;
        c4[0] = b2f(r[0]); c4[1] = b2f(r[1]); c4[2] = b2f(r[2]); c4[3] = b2f(r[3]);
    }
    const int x1 = (int)(c4[0] * 0.0625f);
    const int y1 = (int)(c4[1] * 0.0625f);
    const int x2 = (int)(c4[2] * 0.0625f);
    const int y2 = (int)(c4[3] * 0.0625f);
    const int h = y2 - y1 + 1;
    const int w = x2 - x1 + 1;
    if (t < 7) {
        rs[t] = y1 + (t * h) / 7;
        re_[t] = y1 + ((t + 1) * h + 6) / 7;
        cs[t] = x1 + (t * w) / 7;
        ce_[t] = x1 + ((t + 1) * w + 6) / 7;
    }
    __syncthreads();

    const float* featf = (const float*)feat_;
    const U16* featu = (const U16*)feat_;

    for (int o = t; o < 32 * 49; o += 256) {
        const int ch = ch0 + o / 49;
        const int b = o % 49;
        const int ph = b / 7;
        const int pw = b - ph * 7;
        const int r0 = rs[ph], r1 = re_[ph];
        const int c0 = cs[pw], c1 = ce_[pw];
        const int base = ch * (HF * WF);
        float m = -1.0e4f;
        if (f32w) {
            for (int r = r0; r < r1; ++r) {
                const int rr = r < (HF - 1) ? r : (HF - 1);
                const float* fr = featf + base + rr * WF;
                for (int c = c0; c < c1; ++c) {
                    const int cc = c < (WF - 1) ? c : (WF - 1);
                    const float v = fr[cc];
                    m = (m > v) ? m : v;
                }
            }
        } else {
            for (int r = r0; r < r1; ++r) {
                const int rr = r < (HF - 1) ? r : (HF - 1);
                const U16* fr = featu + base + rr * WF;
                for (int c = c0; c < c1; ++c) {
                    const int cc = c < (WF - 1) ? c : (WF - 1);
                    const float v = b2f(fr[cc]);
                    m = (m > v) ? m : v;
                }
            }
        }
        m = fminf(fmaxf(m, -1.0e4f), 1.0e4f);
        pool[(size_t)n * FC_IN + ch * 49 + b] = f2b(m);
    }
}

// ---------------------------------------------------------------------------
// Fused-transpose GEMM, 2-phase double-buffered:
//   Cpart[s] = A[M,K](bf16) @ B[K,N](f32 or bf16) over k in [s*Ks,(s+1)*Ks).
// 128x128 tile, BK=32, 256 thr = 2x2 waves each 64x64 (16 mfma 16x16x32).
// Pipeline per iter: frag-read buf[cur] -> stage tile t+1 into buf[nxt]
// (gld_lds A + ds_write B regs) -> reg-load B(t+2) -> MFMA -> barrier.
// B write map: thread owns cols {lane, lane+64} x 8 k-rows -> LDS write start
// bank = lane*20 mod 32 (all 8 quads, conflict-free; old 2*lane map was 2x).
// ---------------------------------------------------------------------------
#define GBM 128
#define GBN 128
#define GBK 32
#define BROW 40   // U16 per b_lds row = 80 bytes (64B data + 16B pad)

__launch_bounds__(256, 2)
__global__ void gemm_fused_kernel(const U16* __restrict__ A, int lda,
                                  const void* __restrict__ B, int ldb,
                                  float* __restrict__ Cpart,
                                  int M, int N, int Ks,
                                  const int* __restrict__ flags) {
    __shared__ __align__(16) U16 a_lds[2][GBM * GBK];   // 2 x 8 KB
    __shared__ __align__(16) U16 b_lds[2][GBN * BROW];  // 2 x 10 KB

    const int t = threadIdx.x;
    const int wave = t >> 6, lane = t & 63;
    const int ln = lane & 15, q = lane >> 4;
    const int wm = wave >> 1, wn = wave & 1;
    const int bm = blockIdx.y * GBM, bn = blockIdx.x * GBN;
    const int s = blockIdx.z;
    const int kb = s * Ks;
    float* Cp = Cpart + (size_t)s * M * N;
    const int f32b = flags[0];
    const int nIter = Ks / GBK;

    floatx4 acc[4][4];
#pragma unroll
    for (int i = 0; i < 4; ++i)
#pragma unroll
        for (int j = 0; j < 4; ++j) acc[i][j] = (floatx4)0.0f;

    // A staging: 8 slots of 16 rows; wave handles slots wave*2, wave*2+1
    const int slot0 = wave * 2;
    const int rsl = lane >> 2;          // row within slot
    const int c8 = (lane & 3) * 8;      // k-elem offset
    const U16* Ag0 = A + (size_t)(bm + slot0 * 16 + rsl) * lda + kb + c8;
    const U16* Ag1 = Ag0 + (size_t)16 * lda;
    const int ao0 = slot0 * 512;
    const int ao1 = ao0 + 512;

    // B staging: thread owns cols {lane, lane+64}, k-rows kg..kg+7
    const int cl = lane;
    const int kg = wave * 8;
    const int bo0 = cl * BROW + kg;
    const int bo1 = (cl + 64) * BROW + kg;

    if (f32b) {
        const float* bp = (const float*)B + (size_t)(kb + kg) * ldb + bn + cl;
        float va0[8], va1[8];
        // ---- prologue: stage tile 0, prefetch B(1) regs
#pragma unroll
        for (int j = 0; j < 8; ++j) {
            va0[j] = bp[(size_t)j * ldb];
            va1[j] = bp[(size_t)j * ldb + 64];
        }
        bp += (size_t)GBK * ldb;
        gld_lds16(Ag0, &a_lds[0][ao0], lane);
        gld_lds16(Ag1, &a_lds[0][ao1], lane);
        {
            union { __bf16 b[8]; ushort8 s8; } h0, h1;
#pragma unroll
            for (int j = 0; j < 8; ++j) { h0.b[j] = (__bf16)va0[j]; h1.b[j] = (__bf16)va1[j]; }
            *(ushort8*)&b_lds[0][bo0] = h0.s8;
            *(ushort8*)&b_lds[0][bo1] = h1.s8;
        }
        if (nIter > 1) {
#pragma unroll
            for (int j = 0; j < 8; ++j) {
                va0[j] = bp[(size_t)j * ldb];
                va1[j] = bp[(size_t)j * ldb + 64];
            }
            bp += (size_t)GBK * ldb;
        }
        __syncthreads();

        for (int it = 0; it < nIter; ++it) {
            const int cur = it & 1, nxt = cur ^ 1;
            // fragments of tile it (issued first so MFMA need not wait writes)
            bf16x8 av[4], bv[4];
#pragma unroll
            for (int mt = 0; mt < 4; ++mt)
                av[mt] = *(const bf16x8*)&a_lds[cur][(wm * 64 + mt * 16 + ln) * GBK + q * 8];
#pragma unroll
            for (int nt = 0; nt < 4; ++nt)
                bv[nt] = *(const bf16x8*)&b_lds[cur][(wn * 64 + nt * 16 + ln) * BROW + q * 8];
            // stage tile it+1 into buf[nxt]
            if (it + 1 < nIter) {
                gld_lds16(Ag0 + (it + 1) * GBK, &a_lds[nxt][ao0], lane);
                gld_lds16(Ag1 + (it + 1) * GBK, &a_lds[nxt][ao1], lane);
                union { __bf16 b[8]; ushort8 s8; } h0, h1;
#pragma unroll
                for (int j = 0; j < 8; ++j) { h0.b[j] = (__bf16)va0[j]; h1.b[j] = (__bf16)va1[j]; }
                *(ushort8*)&b_lds[nxt][bo0] = h0.s8;
                *(ushort8*)&b_lds[nxt][bo1] = h1.s8;
            }
            // prefetch B(it+2) regs (after ds_write consumed old values)
            if (it + 2 < nIter) {
#pragma unroll
                for (int j = 0; j < 8; ++j) {
                    va0[j] = bp[(size_t)j * ldb];
                    va1[j] = bp[(size_t)j * ldb + 64];
                }
                bp += (size_t)GBK * ldb;
            }
#pragma unroll
            for (int mt = 0; mt < 4; ++mt)
#pragma unroll
                for (int nt = 0; nt < 4; ++nt)
                    acc[mt][nt] = __builtin_amdgcn_mfma_f32_16x16x32_bf16(
                        av[mt], bv[nt], acc[mt][nt], 0, 0, 0);
            __syncthreads();
        }
    } else {
        const U16* bp = (const U16*)B + (size_t)(kb + kg) * ldb + bn + cl;
        U16 va0[8], va1[8];
#pragma unroll
        for (int j = 0; j < 8; ++j) {
            va0[j] = bp[(size_t)j * ldb];
            va1[j] = bp[(size_t)j * ldb + 64];
        }
        bp += (size_t)GBK * ldb;
        gld_lds16(Ag0, &a_lds[0][ao0], lane);
        gld_lds16(Ag1, &a_lds[0][ao1], lane);
        {
            union { U16 u[8]; ushort8 s8; } h0, h1;
#pragma unroll
            for (int j = 0; j < 8; ++j) { h0.u[j] = va0[j]; h1.u[j] = va1[j]; }
            *(ushort8*)&b_lds[0][bo0] = h0.s8;
            *(ushort8*)&b_lds[0][bo1] = h1.s8;
        }
        if (nIter > 1) {
#pragma unroll
            for (int j = 0; j < 8; ++j) {
                va0[j] = bp[(size_t)j * ldb];
                va1[j] = bp[(size_t)j * ldb + 64];
            }
            bp += (size_t)GBK * ldb;
        }
        __syncthreads();

        for (int it = 0; it < nIter; ++it) {
            const int cur = it & 1, nxt = cur ^ 1;
            bf16x8 av[4], bv[4];
#pragma unroll
            for (int mt = 0; mt < 4; ++mt)
                av[mt] = *(const bf16x8*)&a_lds[cur][(wm * 64 + mt * 16 + ln) * GBK + q * 8];
#pragma unroll
            for (int nt = 0; nt < 4; ++nt)
                bv[nt] = *(const bf16x8*)&b_lds[cur][(wn * 64 + nt * 16 + ln) * BROW + q * 8];
            if (it + 1 < nIter) {
                gld_lds16(Ag0 + (it + 1) * GBK, &a_lds[nxt][ao0], lane);
                gld_lds16(Ag1 + (it + 1) * GBK, &a_lds[nxt][ao1], lane);
                union { U16 u[8]; ushort8 s8; } h0, h1;
#pragma unroll
                for (int j = 0; j < 8; ++j) { h0.u[j] = va0[j]; h1.u[j] = va1[j]; }
                *(ushort8*)&b_lds[nxt][bo0] = h0.s8;
                *(ushort8*)&b_lds[nxt][bo1] = h1.s8;
            }
            if (it + 2 < nIter) {
#pragma unroll
                for (int j = 0; j < 8; ++j) {
                    va0[j] = bp[(size_t)j * ldb];
                    va1[j] = bp[(size_t)j * ldb + 64];
                }
                bp += (size_t)GBK * ldb;
            }
#pragma unroll
            for (int mt = 0; mt < 4; ++mt)
#pragma unroll
                for (int nt = 0; nt < 4; ++nt)
                    acc[mt][nt] = __builtin_amdgcn_mfma_f32_16x16x32_bf16(
                        av[mt], bv[nt], acc[mt][nt], 0, 0, 0);
            __syncthreads();
        }
    }

#pragma unroll
    for (int nt = 0; nt < 4; ++nt) {
        const int col = bn + wn * 64 + nt * 16 + ln;
#pragma unroll
        for (int mt = 0; mt < 4; ++mt) {
            const int row = bm + wm * 64 + mt * 16 + q * 4;
#pragma unroll
            for (int r = 0; r < 4; ++r)
                Cp[(size_t)(row + r) * N + col] = acc[mt][nt][r];
        }
    }
}

// ---------------------------------------------------------------------------
// m97-style GEMM, B pre-transposed bf16 (kept for the small heads matmul).
// ---------------------------------------------------------------------------
__launch_bounds__(256, 2)
__global__ void gemm_tn_kernel(const U16* __restrict__ A, int lda,
                               const U16* __restrict__ BT, int ldb,
                               float* __restrict__ Cpart,
                               int M, int N, int Ks) {
    __shared__ __align__(16) U16 a_lds[GBM * GBK];  // 8 KB
    __shared__ __align__(16) U16 b_lds[GBN * GBK];  // 8 KB

    const int t = threadIdx.x;
    const int wave = t >> 6, lane = t & 63;
    const int ln = lane & 15, q = lane >> 4;
    const int wm = wave >> 1, wn = wave & 1;
    const int bm = blockIdx.y * GBM, bn = blockIdx.x * GBN;
    const int s = blockIdx.z;
    const int kb = s * Ks, ke = kb + Ks;
    float* Cp = Cpart + (size_t)s * M * N;

    floatx4 acc[4][4];
#pragma unroll
    for (int i = 0; i < 4; ++i)
#pragma unroll
        for (int j = 0; j < 4; ++j) acc[i][j] = (floatx4)0.0f;

    const int slot0 = wave * 2;
    const int rsl = lane >> 2;
    const int c8 = (lane & 3) * 8;
    const U16* Ag0 = A + (size_t)(bm + slot0 * 16 + rsl) * lda + c8;
    const U16* Ag1 = A + (size_t)(bm + slot0 * 16 + 16 + rsl) * lda + c8;
    const U16* Bg0 = BT + (size_t)(bn + slot0 * 16 + rsl) * ldb + c8;
    const U16* Bg1 = BT + (size_t)(bn + slot0 * 16 + 16 + rsl) * ldb + c8;
    U16* al0 = &a_lds[slot0 * 512];
    U16* al1 = &a_lds[(slot0 + 1) * 512];
    U16* bl0 = &b_lds[slot0 * 512];
    U16* bl1 = &b_lds[(slot0 + 1) * 512];

    for (int k0 = kb; k0 < ke; k0 += GBK) {
        gld_lds16(Ag0 + k0, al0, lane);
        gld_lds16(Ag1 + k0, al1, lane);
        gld_lds16(Bg0 + k0, bl0, lane);
        gld_lds16(Bg1 + k0, bl1, lane);
        __syncthreads();

        bf16x8 av[4], bv[4];
#pragma unroll
        for (int mt = 0; mt < 4; ++mt)
            av[mt] = *(const bf16x8*)&a_lds[(wm * 64 + mt * 16 + ln) * GBK + q * 8];
#pragma unroll
        for (int nt = 0; nt < 4; ++nt)
            bv[nt] = *(const bf16x8*)&b_lds[(wn * 64 + nt * 16 + ln) * GBK + q * 8];

#pragma unroll
        for (int mt = 0; mt < 4; ++mt)
#pragma unroll
            for (int nt = 0; nt < 4; ++nt)
                acc[mt][nt] = __builtin_amdgcn_mfma_f32_16x16x32_bf16(
                    av[mt], bv[nt], acc[mt][nt], 0, 0, 0);
        __syncthreads();
    }

#pragma unroll
    for (int nt = 0; nt < 4; ++nt) {
        const int col = bn + wn * 64 + nt * 16 + ln;
#pragma unroll
        for (int mt = 0; mt < 4; ++mt) {
            const int row = bm + wm * 64 + mt * 16 + q * 4;
#pragma unroll
            for (int r = 0; r < 4; ++r)
                Cp[(size_t)(row + r) * N + col] = acc[mt][nt][r];
        }
    }
}

// sum partials + bias, optional relu, -> bf16
__global__ void reduce_act_kernel(const float* __restrict__ Cpart,
                                  const U16* __restrict__ bias,
                                  U16* __restrict__ Cout,
                                  int MN, int N, int S, int do_relu) {
    const int i4 = (blockIdx.x * 256 + threadIdx.x) * 4;
    if (i4 >= MN) return;
    floatx4 sum = *(const floatx4*)&Cpart[i4];
    for (int s = 1; s < S; ++s)
        sum += *(const floatx4*)&Cpart[(size_t)s * MN + i4];
    const int nb = i4 & (N - 1);
    U16 o[4];
#pragma unroll
    for (int j = 0; j < 4; ++j) {
        float v = sum[j] + b2f(bias[nb + j]);
        if (do_relu) { v = v > 0.0f ? v : 0.0f; v = fminf(v, 1.0e4f); }
        o[j] = f2b(v);
    }
    *(unsigned long long*)&Cout[i4] = *(unsigned long long*)o;
}

// pack heads transposed: WhT [128][4096] bf16 (rows>=105 zero), bh[128]
__global__ void pack_headsT_kernel(const void* __restrict__ W_loc,
                                   const void* __restrict__ W_score,
                                   const U16* __restrict__ b_loc,
                                   const U16* __restrict__ b_score,
                                   const int* __restrict__ flags,
                                   U16* __restrict__ WhT, U16* __restrict__ bh) {
    const int idx = blockIdx.x * 256 + threadIdx.x;   // 128*4096
    const int c = idx >> 12;
    const int k = idx & 4095;
    const int f32w = flags[0];
    U16 v = 0;
    if (f32w) {
        if (c < 84) v = f2b(((const float*)W_loc)[(size_t)k * 84 + c]);
        else if (c < NHEAD) v = f2b(((const float*)W_score)[(size_t)k * 21 + (c - 84)]);
    } else {
        if (c < 84) v = ((const U16*)W_loc)[(size_t)k * 84 + c];
        else if (c < NHEAD) v = ((const U16*)W_score)[(size_t)k * 21 + (c - 84)];
    }
    WhT[idx] = v;
    if (idx < NHEAD_PAD) {
        U16 bb = 0;
        if (idx < 84) bb = b_loc[idx];
        else if (idx < NHEAD) bb = b_score[idx - 84];
        bh[idx] = bb;
    }
}

// reduce head partials [S][512][128] + bias -> scattered output
__global__ void head_reduce_kernel(const float* __restrict__ Cpart,
                                   const U16* __restrict__ bh,
                                   const int* __restrict__ flags,
                                   void* __restrict__ out, int S) {
    const int idx = blockIdx.x * 256 + threadIdx.x;
    if (idx >= NROIS * NHEAD_PAD) return;
    const int m = idx >> 7;
    const int c = idx & 127;
    float s = 0.0f;
    for (int ss = 0; ss < S; ++ss)
        s += Cpart[(size_t)ss * (NROIS * NHEAD_PAD) + idx];
    s += b2f(bh[c]);
    if (c >= NHEAD) return;
    const int dst = (c < 84) ? (m * 84 + c) : (OUT_LOCS + m * 21 + (c - 84));
    if (flags[0]) ((float*)out)[dst] = s;
    else ((U16*)out)[dst] = f2b(s);
}

// ======================= fallback path (round-2, verified) =================
#define BM 128
#define BN 64
#define BK 32

__launch_bounds__(256, 2)
__global__ void gemm_bias_kernel(const U16* __restrict__ A,
                                 const void* __restrict__ B,
                                 const U16* __restrict__ bias,
                                 U16* __restrict__ Cout,
                                 int M, int N, int K, int do_relu,
                                 const int* __restrict__ flags, int use_flag) {
    __shared__ U16 a_lds[BM][BK];
    __shared__ U16 b_lds[BK][80];
    const int b_f32 = use_flag ? flags[0] : 0;
    const int t = threadIdx.x;
    const int wave = t >> 6, lane = t & 63;
    const int ln = lane & 15, q = lane >> 4;
    const int wm = wave >> 1, wn = wave & 1;
    const int bm = blockIdx.y * BM, bn = blockIdx.x * BN;
    floatx4 acc[4][2];
#pragma unroll
    for (int i = 0; i < 4; ++i)
#pragma unroll
        for (int j = 0; j < 2; ++j) acc[i][j] = (floatx4)0.0f;
    const int arow = t >> 2, acol = (t & 3) * 8;
    const int bk = t >> 3, bn8 = (t & 7) * 8;
    const int browp = ((bk & 7) << 2) | (bk >> 3);
    const U16* Ap0 = A + (size_t)(bm + arow) * K + acol;
    const U16* Ap1 = A + (size_t)(bm + 64 + arow) * K + acol;
    const U16* Bp16 = (const U16*)B + (size_t)bk * N + bn + bn8;
    const float* Bp32 = (const float*)B + (size_t)bk * N + bn + bn8;
    for (int k0 = 0; k0 < K; k0 += BK) {
        *(floatx4*)&a_lds[arow][acol] = *(const floatx4*)(Ap0 + k0);
        *(floatx4*)&a_lds[64 + arow][acol] = *(const floatx4*)(Ap1 + k0);
        if (b_f32) {
            const float* src = Bp32 + (size_t)k0 * N;
            union { U16 u[8]; floatx4 v; } tmp;
#pragma unroll
            for (int j = 0; j < 8; ++j) tmp.u[j] = f2b(src[j]);
            *(floatx4*)&b_lds[browp][bn8] = tmp.v;
        } else {
            *(floatx4*)&b_lds[browp][bn8] = *(const floatx4*)(Bp16 + (size_t)k0 * N);
        }
        __syncthreads();
        bf16x8 av[4];
#pragma unroll
        for (int mt = 0; mt < 4; ++mt)
            av[mt] = *(const bf16x8*)&a_lds[wm * 64 + mt * 16 + ln][q * 8];
        union { U16 u[8]; bf16x8 v; } bu[2];
#pragma unroll
        for (int nt = 0; nt < 2; ++nt) {
            const int n = wn * 32 + nt * 16 + ln;
#pragma unroll
            for (int j = 0; j < 8; ++j) bu[nt].u[j] = b_lds[(j << 2) | q][n];
        }
#pragma unroll
        for (int mt = 0; mt < 4; ++mt)
#pragma unroll
            for (int nt = 0; nt < 2; ++nt)
                acc[mt][nt] = __builtin_amdgcn_mfma_f32_16x16x32_bf16(
                    av[mt], bu[nt].v, acc[mt][nt], 0, 0, 0);
        __syncthreads();
    }
#pragma unroll
    for (int nt = 0; nt < 2; ++nt) {
        const int col = bn + wn * 32 + nt * 16 + ln;
        const float bv = b2f(bias[col]);
#pragma unroll
        for (int mt = 0; mt < 4; ++mt) {
            const int row = bm + wm * 64 + mt * 16 + q * 4;
#pragma unroll
            for (int r = 0; r < 4; ++r) {
                float v = acc[mt][nt][r] + bv;
                if (do_relu) { v = v > 0.0f ? v : 0.0f; v = fminf(v, 1.0e4f); }
                Cout[(size_t)(row + r) * N + col] = f2b(v);
            }
        }
    }
}

__global__ void pack_heads_kernel(const void* __restrict__ W_loc,
                                  const void* __restrict__ W_score,
                                  const U16* __restrict__ b_loc,
                                  const U16* __restrict__ b_score,
                                  const int* __restrict__ flags,
                                  U16* __restrict__ Wh, U16* __restrict__ bh) {
    const int k = blockIdx.x;
    const int c = threadIdx.x;
    const int f32w = flags[0];
    U16 v = 0;
    if (f32w) {
        if (c < 84) v = f2b(((const float*)W_loc)[k * 84 + c]);
        else if (c < NHEAD) v = f2b(((const float*)W_score)[k * 21 + (c - 84)]);
    } else {
        if (c < 84) v = ((const U16*)W_loc)[k * 84 + c];
        else if (c < NHEAD) v = ((const U16*)W_score)[k * 21 + (c - 84)];
    }
    Wh[k * NHEAD_PAD + c] = v;
    if (k == 0) {
        U16 bb = 0;
        if (c < 84) bb = b_loc[c];
        else if (c < NHEAD) bb = b_score[c - 84];
        bh[c] = bb;
    }
}

__global__ void scatter_out_kernel(const U16* __restrict__ Chead,
                                   const int* __restrict__ flags,
                                   void* __restrict__ out) {
    const int idx = blockIdx.x * 256 + threadIdx.x;
    if (idx >= NROIS * NHEAD) return;
    const int f32o = flags[0];
    const int m = idx / NHEAD;
    const int c = idx - m * NHEAD;
    const U16 v = Chead[m * NHEAD_PAD + c];
    const int dst = (c < 84) ? (m * 84 + c) : (OUT_LOCS + m * 21 + (c - 84));
    if (f32o) ((float*)out)[dst] = b2f(v);
    else ((U16*)out)[dst] = v;
}

// ===========================================================================
extern "C" void kernel_launch(void* const* d_in, const int* in_sizes, int n_in,
                              void* d_out, int out_size, void* d_ws, size_t ws_size,
                              hipStream_t stream) {
    const void* x       = d_in[0];
    const void* rois    = d_in[1];
    const void* W1      = d_in[2];
    const U16* b1       = (const U16*)d_in[3];
    const void* W2      = d_in[4];
    const U16* b2       = (const U16*)d_in[5];
    const void* W_loc   = d_in[6];
    const U16* b_loc    = (const U16*)d_in[7];
    const void* W_score = d_in[8];
    const U16* b_score  = (const U16*)d_in[9];

    int* flags = (int*)d_ws;
    char* p = (char*)d_ws + 256;
    U16* pool = (U16*)p;                       p += (size_t)NROIS * FC_IN * 2;
    U16* fc1  = (U16*)p;                       p += (size_t)NROIS * FC_DIM * 2;
    U16* fc2  = (U16*)p;                       p += (size_t)NROIS * FC_DIM * 2;

    detect_kernel<<<1, 256, 0, stream>>>((const unsigned int*)W1,
                                         (const unsigned int*)rois, flags);
    roi_pool_kernel<<<dim3(NROIS, 16), 256, 0, stream>>>(x, rois, flags, pool);

    // fast path: fused-transpose GEMMs, splitK=8 partials (~103 MB of ws)
    char* pf = p;
    U16* WhT = (U16*)pf;  pf += (size_t)NHEAD_PAD * FC_DIM * 2;
    U16* bh  = (U16*)pf;  pf += 256;
    float* Cpart = (float*)pf; pf += (size_t)8 * NROIS * FC_DIM * 4;
    const size_t need_fast = (size_t)(pf - (char*)d_ws);

    if (ws_size >= need_fast) {
        pack_headsT_kernel<<<(NHEAD_PAD * FC_DIM) / 256, 256, 0, stream>>>(
            W_loc, W_score, b_loc, b_score, flags, WhT, bh);

        // FC1: M=512 N=4096 K=25088, splitK=8 (Ks=3136), grid 1024 blocks.
        gemm_fused_kernel<<<dim3(FC_DIM / GBN, NROIS / GBM, 8), 256, 0, stream>>>(
            pool, FC_IN, W1, FC_DIM, Cpart, NROIS, FC_DIM, FC_IN / 8, flags);
        reduce_act_kernel<<<(NROIS * FC_DIM / 4) / 256, 256, 0, stream>>>(
            Cpart, b1, fc1, NROIS * FC_DIM, FC_DIM, 8, 1);

        // FC2: K=4096, splitK=8 (Ks=512)
        gemm_fused_kernel<<<dim3(FC_DIM / GBN, NROIS / GBM, 8), 256, 0, stream>>>(
            fc1, FC_DIM, W2, FC_DIM, Cpart, NROIS, FC_DIM, FC_DIM / 8, flags);
        reduce_act_kernel<<<(NROIS * FC_DIM / 4) / 256, 256, 0, stream>>>(
            Cpart, b2, fc2, NROIS * FC_DIM, FC_DIM, 8, 1);

        // heads: N=128, K=4096, splitK=32 (Ks=128) — small, keep bf16-BT path
        gemm_tn_kernel<<<dim3(1, NROIS / GBM, 32), 256, 0, stream>>>(
            fc2, FC_DIM, WhT, FC_DIM, Cpart, NROIS, NHEAD_PAD, FC_DIM / 32);
        head_reduce_kernel<<<(NROIS * NHEAD_PAD) / 256, 256, 0, stream>>>(
            Cpart, bh, flags, d_out, 32);
    } else {
        // fallback (round-2 verified path, ~36 MB ws)
        U16* Wh    = (U16*)p;
        U16* bhf   = Wh + (size_t)FC_DIM * NHEAD_PAD;
        U16* Chead = bhf + NHEAD_PAD;
        pack_heads_kernel<<<FC_DIM, NHEAD_PAD, 0, stream>>>(W_loc, W_score, b_loc,
                                                            b_score, flags, Wh, bhf);
        gemm_bias_kernel<<<dim3(FC_DIM / BN, NROIS / BM), 256, 0, stream>>>(
            pool, W1, b1, fc1, NROIS, FC_DIM, FC_IN, 1, flags, 1);
        gemm_bias_kernel<<<dim3(FC_DIM / BN, NROIS / BM), 256, 0, stream>>>(
            fc1, W2, b2, fc2, NROIS, FC_DIM, FC_DIM, 1, flags, 1);
        gemm_bias_kernel<<<dim3(NHEAD_PAD / BN, NROIS / BM), 256, 0, stream>>>(
            fc2, Wh, bhf, Chead, NROIS, NHEAD_PAD, FC_DIM, 0, flags, 0);
        scatter_out_kernel<<<(NROIS * NHEAD + 255) / 256, 256, 0, stream>>>(
            Chead, flags, d_out);
    }
}